// Round 1
// 1555.893 us; speedup vs baseline: 1.0649x; 1.0649x over previous
//
#include <hip/hip_runtime.h>

#define S 2048
#define HID 5120
#define NH 40
#define HD 128

typedef unsigned short u16;
typedef __attribute__((ext_vector_type(8))) short short8;
typedef __attribute__((ext_vector_type(4))) float f32x4;

__device__ __forceinline__ u16 f2bf(float f) {
  union { float f; unsigned u; } x; x.f = f;
  unsigned r = x.u + 0x7fffu + ((x.u >> 16) & 1u);
  return (u16)(r >> 16);
}

// async global->LDS, 16B per lane; LDS dest = wave-uniform base + lane*16
__device__ __forceinline__ void gl_lds16(const void* g, void* l) {
  __builtin_amdgcn_global_load_lds((__attribute__((address_space(1))) void*)g,
                                   (__attribute__((address_space(3))) void*)l,
                                   16, 0, 0);
}

// ---------------- fp32 -> bf16 convert ----------------
__global__ __launch_bounds__(256) void cvt4(const float4* __restrict__ s,
                                            ushort4* __restrict__ d, int n4) {
  int i = blockIdx.x * 256 + threadIdx.x;
  if (i >= n4) return;
  float4 v = s[i];
  ushort4 o;
  o.x = f2bf(v.x); o.y = f2bf(v.y); o.z = f2bf(v.z); o.w = f2bf(v.w);
  d[i] = o;
}

// ---------------- 256x256 8-phase pipelined bf16 GEMM ----------------
// C[M,N] = A[M,K] * B[N,K]^T.  M = 2048 fixed (8 m-tiles), grid = 8 * (N/256),
// m-tile = blockIdx & 7 (== XCD id under round-robin dispatch -> A-panel stays
// in that XCD's L2), n-tile = blockIdx >> 3.
// 8 waves (2M x 4N), per-wave output 128x64 (acc[8][4] f32x4).
// LDS: 2 K-tile double buffer, A/B each [256][64] bf16, XOR-swizzled col-blocks
// (LDS[row][cb] = G[row][cb ^ (row&7)], cb = 16B block) -> conflict-free b128 reads.
// Schedule per K-tile group (4 phases), counted vmcnt (never 0 in steady loop):
//  ph1: rd B(t) x8 + A(t)q1; stage A(t+1)h1;              bar; mfma q0; bar
//  ph2: rd A(t)q2;           stage B(t+2)h0;              bar; mfma q1; bar
//  ph3: rd A(t)q3;           stage B(t+2)h1;              bar; mfma q2; bar
//  ph4: vmcnt(4) [retires B(t+1)h0/h1 + A(t+1)h0/h1, leaves B(t+2)x2 in flight];
//       bar; rd A(t+1)q0 (other buf); mfma q3; stage A(t+2)h0; bar
__global__ __launch_bounds__(512, 2) void gemm256(
    const u16* __restrict__ A, const u16* __restrict__ B,
    int N, int K,
    float* __restrict__ C,
    u16* __restrict__ qb, u16* __restrict__ kb, u16* __restrict__ vtb,
    int mode)
{
  __shared__ __align__(16) u16 As[2][16384];   // [buf][256*64]
  __shared__ __align__(16) u16 Bs[2][16384];

  const int tid = threadIdx.x;
  const int lane = tid & 63;
  const int wave = tid >> 6;
  const int wm = wave >> 2, wn = wave & 3;
  const int l16 = lane & 15, quad = lane >> 4;

  const int m0 = (blockIdx.x & 7) << 8;
  const int n0 = (blockIdx.x >> 3) << 8;

  // ---- staging addresses (each STAGE_* = one 128-row half = 2 loads/wave) ----
  const int srow = wave * 8 + (lane >> 3);            // row within half, load 0
  const int scb  = (lane & 7) ^ ((lane >> 3) & 7);    // pre-swizzled source col-block
  const u16* Abase = A + (long)(m0 + srow) * K + scb * 8;
  const u16* Bbase = B + (long)(n0 + srow) * K + scb * 8;
  u16* AsW = &As[0][0] + wave * 512;                  // wave-uniform LDS base
  u16* BsW = &Bs[0][0] + wave * 512;

  // ---- fragment read addresses ----
  const u16* ArBase = &As[0][0] + (wm * 128 + l16) * 64;
  const u16* BrBase = &Bs[0][0] + (wn * 64 + l16) * 64;
  const int acb0 = ((quad) ^ (l16 & 7)) * 8;          // kk=0 col-block (swizzled)
  const int acb1 = ((4 + quad) ^ (l16 & 7)) * 8;      // kk=1

  f32x4 acc[8][4];
#pragma unroll
  for (int i = 0; i < 8; ++i)
#pragma unroll
    for (int j = 0; j < 4; ++j) acc[i][j] = (f32x4){0.f, 0.f, 0.f, 0.f};

  short8 aP[2][2], aN[2][2], brg[4][2];

  const int nt = K >> 6;   // 64-wide K-tiles (80 for K=5120)

#define STAGE_A(bufi, h, kt) do {                                         \
    const u16* g_ = Abase + (long)(h) * 128 * K + (long)(kt) * 64;        \
    gl_lds16(g_,           AsW + (bufi) * 16384 + (h) * 8192);            \
    gl_lds16(g_ + 64L * K, AsW + (bufi) * 16384 + (h) * 8192 + 4096);     \
  } while (0)

#define STAGE_B(bufi, h, kt) do {                                         \
    const u16* g_ = Bbase + (long)(h) * 128 * K + (long)(kt) * 64;        \
    gl_lds16(g_,           BsW + (bufi) * 16384 + (h) * 8192);            \
    gl_lds16(g_ + 64L * K, BsW + (bufi) * 16384 + (h) * 8192 + 4096);     \
  } while (0)

#define RD_A(dst, bufi, q) do {                                           \
    const u16* p_ = ArBase + (bufi) * 16384 + (q) * 2048;                 \
    dst[0][0] = *(const short8*)(p_ + acb0);                              \
    dst[0][1] = *(const short8*)(p_ + acb1);                              \
    dst[1][0] = *(const short8*)(p_ + 1024 + acb0);                       \
    dst[1][1] = *(const short8*)(p_ + 1024 + acb1);                       \
  } while (0)

#define RD_B(bufi) do {                                                   \
    const u16* p_ = BrBase + (bufi) * 16384;                              \
    brg[0][0] = *(const short8*)(p_ + acb0);                              \
    brg[0][1] = *(const short8*)(p_ + acb1);                              \
    brg[1][0] = *(const short8*)(p_ + 1024 + acb0);                       \
    brg[1][1] = *(const short8*)(p_ + 1024 + acb1);                       \
    brg[2][0] = *(const short8*)(p_ + 2048 + acb0);                       \
    brg[2][1] = *(const short8*)(p_ + 2048 + acb1);                       \
    brg[3][0] = *(const short8*)(p_ + 3072 + acb0);                       \
    brg[3][1] = *(const short8*)(p_ + 3072 + acb1);                       \
  } while (0)

#define MFMA1(mi, j, ar) do {                                                             \
    acc[mi][j] = __builtin_amdgcn_mfma_f32_16x16x32_bf16(ar[0], brg[j][0], acc[mi][j], 0, 0, 0); \
    acc[mi][j] = __builtin_amdgcn_mfma_f32_16x16x32_bf16(ar[1], brg[j][1], acc[mi][j], 0, 0, 0); \
  } while (0)

#define MFMA_Q(q, a) do {                                                 \
    MFMA1((q)*2 + 0, 0, a[0]); MFMA1((q)*2 + 0, 1, a[0]);                 \
    MFMA1((q)*2 + 0, 2, a[0]); MFMA1((q)*2 + 0, 3, a[0]);                 \
    MFMA1((q)*2 + 1, 0, a[1]); MFMA1((q)*2 + 1, 1, a[1]);                 \
    MFMA1((q)*2 + 1, 2, a[1]); MFMA1((q)*2 + 1, 3, a[1]);                 \
  } while (0)

#define ASM_VMCNT(n) asm volatile("s_waitcnt vmcnt(" #n ")" ::: "memory")
#define BAR() __builtin_amdgcn_s_barrier()
#define PRIO1 __builtin_amdgcn_s_setprio(1)
#define PRIO0 __builtin_amdgcn_s_setprio(0)

// S1: tile t+1 exists (stage A(t+1)h1, read its q0). S2: tile t+2 exists.
#define KGROUP(S1, S2, VMN) do {                                          \
    const int bi = t & 1, bn = bi ^ 1;                                    \
    /* ph1 */                                                             \
    RD_B(bi);                                                             \
    RD_A(aN, bi, 1);                                                      \
    if (S1) STAGE_A(bn, 1, t + 1);                                        \
    BAR();                                                                \
    PRIO1; MFMA_Q(0, aP); PRIO0;                                          \
    BAR();                                                                \
    /* ph2 */                                                             \
    RD_A(aP, bi, 2);                                                      \
    if (S2) STAGE_B(bi, 0, t + 2);                                        \
    BAR();                                                                \
    PRIO1; MFMA_Q(1, aN); PRIO0;                                          \
    BAR();                                                                \
    /* ph3 */                                                             \
    RD_A(aN, bi, 3);                                                      \
    if (S2) STAGE_B(bi, 1, t + 2);                                        \
    BAR();                                                                \
    PRIO1; MFMA_Q(2, aP); PRIO0;                                          \
    BAR();                                                                \
    /* ph4 */                                                             \
    ASM_VMCNT(VMN);                                                       \
    __builtin_amdgcn_sched_barrier(0);                                    \
    BAR();                                                                \
    if (S1) RD_A(aP, bn, 0);                                              \
    PRIO1; MFMA_Q(3, aN); PRIO0;                                          \
    if (S2) STAGE_A(bi, 0, t + 2);                                        \
    BAR();                                                                \
  } while (0)

  // ---- prologue: tile0 (4 halves) + B(1) (2 halves); vmcnt(4) retires tile0 ----
  STAGE_A(0, 0, 0); STAGE_A(0, 1, 0);
  STAGE_B(0, 0, 0); STAGE_B(0, 1, 0);
  STAGE_B(1, 0, 1); STAGE_B(1, 1, 1);
  ASM_VMCNT(4);
  __builtin_amdgcn_sched_barrier(0);
  BAR();
  STAGE_A(1, 0, 1);       // A(1)h0 in flight (mimics steady ph4 issue slot)
  RD_A(aP, 0, 0);         // tile0 quad0 into regs

  for (int t = 0; t < nt - 2; ++t) { KGROUP(1, 1, 4); }
  { int t = nt - 2; KGROUP(1, 0, 0); }   // drain: confirm last tile fully
  { int t = nt - 1; KGROUP(0, 0, 0); }

  // ---- epilogue ----
  if (mode == 0) {
#pragma unroll
    for (int mi = 0; mi < 8; ++mi)
#pragma unroll
      for (int r = 0; r < 4; ++r) {
        int row = m0 + wm * 128 + mi * 16 + quad * 4 + r;
        float* cp = C + (long)row * N + n0 + wn * 64 + l16;
#pragma unroll
        for (int j = 0; j < 4; ++j) cp[j * 16] = acc[mi][j][r];
      }
  } else {
    // n-tile is 256 wide = 2 heads; which-of-q/k/v is block-uniform (256 | 5120)
    const int which = n0 / HID;
    const int hbase = (n0 % HID) >> 7;
    const float qs = 0.08838834764831845f;  // 1/sqrt(128), folded into q
#pragma unroll
    for (int mi = 0; mi < 8; ++mi)
#pragma unroll
      for (int j = 0; j < 4; ++j) {
        int colIn = wn * 64 + j * 16 + l16;    // 0..255
        int head = hbase + (colIn >> 7);
        int d = colIn & 127;
#pragma unroll
        for (int r = 0; r < 4; ++r) {
          int sI = m0 + wm * 128 + mi * 16 + quad * 4 + r;
          float v = acc[mi][j][r];
          if (which == 0)      qb[((long)head * S + sI) * HD + d] = f2bf(v * qs);
          else if (which == 1) kb[((long)head * S + sI) * HD + d] = f2bf(v);
          else                 vtb[((long)head * HD + d) * S + sI] = f2bf(v);  // V^T
        }
      }
  }

#undef STAGE_A
#undef STAGE_B
#undef RD_A
#undef RD_B
#undef MFMA1
#undef MFMA_Q
#undef ASM_VMCNT
#undef BAR
#undef PRIO1
#undef PRIO0
#undef KGROUP
}

// ---------------- flash attention: Q-tile 64, K-tile 64 ----------------
// q,k: [NH][S][HD] bf16 (q pre-scaled), v: [NH][HD][S] bf16 (transposed)
// out: [S][HID] bf16
__global__ __launch_bounds__(256) void attn_kernel(
    const u16* __restrict__ qg, const u16* __restrict__ kg,
    const u16* __restrict__ vg, u16* __restrict__ og)
{
  __shared__ __align__(16) u16 Qs[64 * 128];   // [q][d]
  __shared__ __align__(16) u16 Ks[64 * 128];   // [k][d]; aliased by Ps[64][64]
  __shared__ __align__(16) u16 Vs[128 * 64];   // [d][k]  (V^T tile)
  __shared__ float redm[2][64];
  __shared__ float reds[2][64];

  const int tid = threadIdx.x;
  const int lane = tid & 63;
  const int wid = tid >> 6;
  const int wm = wid >> 1, wn = wid & 1;
  const int l16 = lane & 15, quad = lane >> 4;
  const int qt = blockIdx.x;
  const int h = blockIdx.y;
  const int q0 = qt * 64;

  u16* Ps = Ks;  // P overwrites K tile after S-compute (barrier-protected)

  {
    const u16* src = qg + ((long)h * S + q0) * HD;
#pragma unroll
    for (int cc = 0; cc < 4; ++cc) {
      int c = wid * 4 + cc;
      int row = c * 4 + (lane >> 4);
      int cb = (lane & 15) ^ (row & 7);
      gl_lds16(src + row * HD + cb * 8, &Qs[c * 512]);
    }
  }

  f32x4 acc_o[2][4];
#pragma unroll
  for (int i = 0; i < 2; ++i)
#pragma unroll
    for (int j = 0; j < 4; ++j)
      acc_o[i][j] = (f32x4){0.f, 0.f, 0.f, 0.f};
  float m_st[2][4], l_st[2][4];
#pragma unroll
  for (int i = 0; i < 2; ++i)
#pragma unroll
    for (int r = 0; r < 4; ++r) { m_st[i][r] = -1e30f; l_st[i][r] = 0.f; }

  for (int kt = 0; kt <= qt; ++kt) {
    __syncthreads();  // prev iter's Ps/Vs reads done (also covers Q stage on iter 0)
    {
      const u16* ksrc = kg + ((long)h * S + kt * 64) * HD;
#pragma unroll
      for (int cc = 0; cc < 4; ++cc) {
        int c = wid * 4 + cc;
        int row = c * 4 + (lane >> 4);
        int cb = (lane & 15) ^ (row & 7);
        gl_lds16(ksrc + row * HD + cb * 8, &Ks[c * 512]);
      }
      const u16* vsrc = vg + (long)h * HD * S + kt * 64;
#pragma unroll
      for (int cc = 0; cc < 4; ++cc) {
        int c = wid * 4 + cc;
        int row = c * 8 + (lane >> 3);
        int cb = (lane & 7) ^ (row & 7);
        gl_lds16(vsrc + (long)row * S + cb * 8, &Vs[c * 512]);
      }
    }
    __syncthreads();

    // ---- S = Q K^T (64x64, each wave 32x32) ----
    f32x4 acc_s[2][2];
#pragma unroll
    for (int i = 0; i < 2; ++i)
#pragma unroll
      for (int j = 0; j < 2; ++j)
        acc_s[i][j] = (f32x4){0.f, 0.f, 0.f, 0.f};
#pragma unroll
    for (int kk = 0; kk < 128; kk += 32) {
      short8 aq[2], bk[2];
      const int cb0 = (kk >> 3) + quad;
#pragma unroll
      for (int i = 0; i < 2; ++i) {
        int row = wm * 32 + i * 16 + l16;
        aq[i] = *(const short8*)&Qs[row * 128 + (cb0 ^ (row & 7)) * 8];
      }
#pragma unroll
      for (int j = 0; j < 2; ++j) {
        int row = wn * 32 + j * 16 + l16;
        bk[j] = *(const short8*)&Ks[row * 128 + (cb0 ^ (row & 7)) * 8];
      }
#pragma unroll
      for (int i = 0; i < 2; ++i)
#pragma unroll
        for (int j = 0; j < 2; ++j)
          acc_s[i][j] = __builtin_amdgcn_mfma_f32_16x16x32_bf16(aq[i], bk[j], acc_s[i][j], 0, 0, 0);
    }

    // ---- causal mask (only diagonal tile) ----
    if (kt == qt) {
#pragma unroll
      for (int i = 0; i < 2; ++i)
#pragma unroll
        for (int j = 0; j < 2; ++j)
#pragma unroll
          for (int r = 0; r < 4; ++r) {
            int row = wm * 32 + i * 16 + quad * 4 + r;
            int col = wn * 32 + j * 16 + l16;
            if (col > row) acc_s[i][j][r] = -1e30f;
          }
    }

    // ---- row max: per-wave shfl over 16 cols, cross-wave via LDS ----
#pragma unroll
    for (int i = 0; i < 2; ++i)
#pragma unroll
      for (int r = 0; r < 4; ++r) {
        float v = fmaxf(acc_s[i][0][r], acc_s[i][1][r]);
        v = fmaxf(v, __shfl_xor(v, 1));
        v = fmaxf(v, __shfl_xor(v, 2));
        v = fmaxf(v, __shfl_xor(v, 4));
        v = fmaxf(v, __shfl_xor(v, 8));
        if (l16 == 0) redm[wn][wm * 32 + i * 16 + quad * 4 + r] = v;
      }
    __syncthreads();  // redm ready; also: all waves done with Ks -> Ps writable

    float alpha[2][4], mnew[2][4], psum[2][4];
#pragma unroll
    for (int i = 0; i < 2; ++i)
#pragma unroll
      for (int r = 0; r < 4; ++r) {
        int row = wm * 32 + i * 16 + quad * 4 + r;
        float mn = fmaxf(m_st[i][r], fmaxf(redm[0][row], redm[1][row]));
        mnew[i][r] = mn;
        alpha[i][r] = __expf(m_st[i][r] - mn);
        m_st[i][r] = mn;
        psum[i][r] = 0.f;
      }
    // P = exp(S - mnew): write bf16 to Ps (C-layout -> LDS -> A-layout)
#pragma unroll
    for (int i = 0; i < 2; ++i)
#pragma unroll
      for (int j = 0; j < 2; ++j)
#pragma unroll
        for (int r = 0; r < 4; ++r) {
          int row = wm * 32 + i * 16 + quad * 4 + r;
          int col = wn * 32 + j * 16 + l16;
          float p = __expf(acc_s[i][j][r] - mnew[i][r]);
          psum[i][r] += p;
          Ps[row * 64 + ((col >> 3) ^ (row & 7)) * 8 + (col & 7)] = f2bf(p);
        }
#pragma unroll
    for (int i = 0; i < 2; ++i)
#pragma unroll
      for (int r = 0; r < 4; ++r) {
        float v = psum[i][r];
        v += __shfl_xor(v, 1);
        v += __shfl_xor(v, 2);
        v += __shfl_xor(v, 4);
        v += __shfl_xor(v, 8);
        if (l16 == 0) reds[wn][wm * 32 + i * 16 + quad * 4 + r] = v;
      }
    __syncthreads();  // Ps + reds ready

    // ---- rescale O, update l ----
#pragma unroll
    for (int i = 0; i < 2; ++i)
#pragma unroll
      for (int r = 0; r < 4; ++r) {
        int row = wm * 32 + i * 16 + quad * 4 + r;
        l_st[i][r] = alpha[i][r] * l_st[i][r] + reds[0][row] + reds[1][row];
#pragma unroll
        for (int j = 0; j < 4; ++j)
          acc_o[i][j][r] *= alpha[i][r];
      }
    // ---- O += P V   (each wave: rows wm*32+32, d-cols wn*64+64) ----
#pragma unroll
    for (int kk = 0; kk < 64; kk += 32) {
      short8 ap[2], bv[4];
      const int cb0 = (kk >> 3) + quad;
#pragma unroll
      for (int i = 0; i < 2; ++i) {
        int m = wm * 32 + i * 16 + l16;
        ap[i] = *(const short8*)&Ps[m * 64 + (cb0 ^ (m & 7)) * 8];
      }
#pragma unroll
      for (int j = 0; j < 4; ++j) {
        int n = wn * 64 + j * 16 + l16;
        bv[j] = *(const short8*)&Vs[n * 64 + (cb0 ^ (n & 7)) * 8];
      }
#pragma unroll
      for (int i = 0; i < 2; ++i)
#pragma unroll
        for (int j = 0; j < 4; ++j)
          acc_o[i][j] = __builtin_amdgcn_mfma_f32_16x16x32_bf16(ap[i], bv[j], acc_o[i][j], 0, 0, 0);
    }
  }

  // ---- epilogue: O / l -> bf16 [S][HID] ----
#pragma unroll
  for (int i = 0; i < 2; ++i)
#pragma unroll
    for (int r = 0; r < 4; ++r) {
      int row = wm * 32 + i * 16 + quad * 4 + r;
      float inv = 1.f / l_st[i][r];
#pragma unroll
      for (int j = 0; j < 4; ++j) {
        int d = wn * 64 + j * 16 + l16;
        og[(long)(q0 + row) * HID + h * HD + d] = f2bf(acc_o[i][j][r] * inv);
      }
    }
}

// ---------------- host ----------------
extern "C" void kernel_launch(void* const* d_in, const int* in_sizes, int n_in,
                              void* d_out, int out_size, void* d_ws, size_t ws_size,
                              hipStream_t stream) {
  const float* hs = (const float*)d_in[0];
  const float* wp = (const float*)d_in[1];
  const float* wo = (const float*)d_in[2];
  float* out = (float*)d_out;
  char* ws = (char*)d_ws;

  // ws layout (bytes)
  u16* hsb = (u16*)(ws);                  //  20,971,520  hs bf16 [2048][5120]
  u16* wpb = (u16*)(ws + 20971520L);      // 157,286,400  W_pack bf16 [15360][5120]
  u16* wob = (u16*)(ws + 178257920L);     //  52,428,800  o_proj bf16 [5120][5120]
  u16* qb  = (u16*)(ws + 230686720L);     //  20,971,520  q bf16 [40][2048][128] (scaled)
  u16* kb  = (u16*)(ws + 251658240L);     //  20,971,520  k bf16 [40][2048][128]
  u16* vtb = (u16*)(ws + 272629760L);     //  20,971,520  v^T bf16 [40][128][2048]
  u16* aob = (u16*)(ws + 293601280L);     //  20,971,520  attn out bf16 [2048][5120]
  if (ws_size < 314572800UL) return;      // need 300 MB

  cvt4<<<10240, 256, 0, stream>>>((const float4*)hs, (ushort4*)hsb, 2621440);
  cvt4<<<76800, 256, 0, stream>>>((const float4*)wp, (ushort4*)wpb, 19660800);
  cvt4<<<25600, 256, 0, stream>>>((const float4*)wo, (ushort4*)wob, 6553600);

  // QKV: [2048,15360] = hs @ W_pack^T, scatter to q/k/v^T   (8 x 60 tiles)
  gemm256<<<dim3(480), dim3(512), 0, stream>>>(hsb, wpb, 15360, 5120,
                                               nullptr, qb, kb, vtb, 1);
  attn_kernel<<<dim3(32, 40), 256, 0, stream>>>(qb, kb, vtb, aob);
  // out: [2048,5120] = attn_out @ o_proj^T                  (8 x 20 tiles)
  gemm256<<<dim3(160), dim3(512), 0, stream>>>(aob, wob, 5120, 5120,
                                               out, nullptr, nullptr, nullptr, 0);
}

// Round 2
// 1540.546 us; speedup vs baseline: 1.0755x; 1.0100x over previous
//
#include <hip/hip_runtime.h>

#define S 2048
#define HID 5120
#define NH 40
#define HD 128

typedef unsigned short u16;
typedef __attribute__((ext_vector_type(8))) short short8;
typedef __attribute__((ext_vector_type(4))) float f32x4;

__device__ __forceinline__ u16 f2bf(float f) {
  union { float f; unsigned u; } x; x.f = f;
  unsigned r = x.u + 0x7fffu + ((x.u >> 16) & 1u);
  return (u16)(r >> 16);
}

// async global->LDS, 16B per lane; LDS dest = wave-uniform base + lane*16
__device__ __forceinline__ void gl_lds16(const void* g, void* l) {
  __builtin_amdgcn_global_load_lds((__attribute__((address_space(1))) void*)g,
                                   (__attribute__((address_space(3))) void*)l,
                                   16, 0, 0);
}

// ---------------- fp32 -> bf16 convert ----------------
__global__ __launch_bounds__(256) void cvt4(const float4* __restrict__ s,
                                            ushort4* __restrict__ d, int n4) {
  int i = blockIdx.x * 256 + threadIdx.x;
  if (i >= n4) return;
  float4 v = s[i];
  ushort4 o;
  o.x = f2bf(v.x); o.y = f2bf(v.y); o.z = f2bf(v.z); o.w = f2bf(v.w);
  d[i] = o;
}

// ---------------- 256x256 8-phase pipelined bf16 GEMM ----------------
// C[M,N] = A[M,K] * B[N,K]^T.  M = 2048 fixed (8 m-tiles).
// Grid = 8 * nslots, nslots = ceil8(N/256).  XCD-aware co-scheduling:
//   x = bid&7 (XCD under round-robin dispatch), j = bid>>3,
//   m-tile = j&7, n-tile = x + 8*(j>>3)  (dead n-slots exit early).
// => concurrent blocks on one XCD = 4 n-panels x all 8 m-tiles, lock-stepped:
//    each B chunk L2-fetched once / hit by 8 blocks, each A chunk hit by 4.
// 8 waves (2M x 4N), per-wave output 128x64 (acc[8][4] f32x4).
// LDS: 2 K-tile double buffer, A/B each [256][64] bf16, XOR-swizzled col-blocks
// (LDS[row][cb] = G[row][cb ^ (row&7)], cb = 16B block) -> conflict-free b128 reads.
// Schedule per K-tile group (4 phases), counted vmcnt (never 0 in steady loop):
//  ph1: rd B(t) x8 + A(t)q1; stage A(t+1)h1;              bar; mfma q0; bar
//  ph2: rd A(t)q2;           stage B(t+2)h0;              bar; mfma q1; bar
//  ph3: rd A(t)q3;           stage B(t+2)h1;              bar; mfma q2; bar
//  ph4: vmcnt(4) [retires B(t+1)h0/h1 + A(t+1)h0/h1, leaves B(t+2)x2 in flight];
//       bar; rd A(t+1)q0 (other buf); mfma q3; stage A(t+2)h0; bar
__global__ __launch_bounds__(512, 2) void gemm256(
    const u16* __restrict__ A, const u16* __restrict__ B,
    int N, int K,
    float* __restrict__ C,
    u16* __restrict__ qb, u16* __restrict__ kb, u16* __restrict__ vtb,
    int mode)
{
  __shared__ __align__(16) u16 As[2][16384];   // [buf][256*64]
  __shared__ __align__(16) u16 Bs[2][16384];

  const int tid = threadIdx.x;
  const int lane = tid & 63;
  const int wave = tid >> 6;
  const int wm = wave >> 2, wn = wave & 3;
  const int l16 = lane & 15, quad = lane >> 4;

  // XCD-aware (m,n) mapping: co-schedule all 8 m's of an n-panel on one XCD
  const int xcd = blockIdx.x & 7;
  const int j = blockIdx.x >> 3;
  const int ntile = xcd + ((j >> 3) << 3);
  if (ntile >= (N >> 8)) return;               // padded slot: whole WG exits
  const int m0 = (j & 7) << 8;
  const int n0 = ntile << 8;

  // ---- staging addresses (each STAGE_* = one 128-row half = 2 loads/wave) ----
  const int srow = wave * 8 + (lane >> 3);            // row within half, load 0
  const int scb  = (lane & 7) ^ ((lane >> 3) & 7);    // pre-swizzled source col-block
  const u16* Abase = A + (long)(m0 + srow) * K + scb * 8;
  const u16* Bbase = B + (long)(n0 + srow) * K + scb * 8;
  u16* AsW = &As[0][0] + wave * 512;                  // wave-uniform LDS base
  u16* BsW = &Bs[0][0] + wave * 512;

  // ---- fragment read addresses ----
  const u16* ArBase = &As[0][0] + (wm * 128 + l16) * 64;
  const u16* BrBase = &Bs[0][0] + (wn * 64 + l16) * 64;
  const int acb0 = ((quad) ^ (l16 & 7)) * 8;          // kk=0 col-block (swizzled)
  const int acb1 = ((4 + quad) ^ (l16 & 7)) * 8;      // kk=1

  f32x4 acc[8][4];
#pragma unroll
  for (int i = 0; i < 8; ++i)
#pragma unroll
    for (int j2 = 0; j2 < 4; ++j2) acc[i][j2] = (f32x4){0.f, 0.f, 0.f, 0.f};

  short8 aP[2][2], aN[2][2], brg[4][2];

  const int nt = K >> 6;   // 64-wide K-tiles (80 for K=5120)

#define STAGE_A(bufi, h, kt) do {                                         \
    const u16* g_ = Abase + (long)(h) * 128 * K + (long)(kt) * 64;        \
    gl_lds16(g_,           AsW + (bufi) * 16384 + (h) * 8192);            \
    gl_lds16(g_ + 64L * K, AsW + (bufi) * 16384 + (h) * 8192 + 4096);     \
  } while (0)

#define STAGE_B(bufi, h, kt) do {                                         \
    const u16* g_ = Bbase + (long)(h) * 128 * K + (long)(kt) * 64;        \
    gl_lds16(g_,           BsW + (bufi) * 16384 + (h) * 8192);            \
    gl_lds16(g_ + 64L * K, BsW + (bufi) * 16384 + (h) * 8192 + 4096);     \
  } while (0)

#define RD_A(dst, bufi, q) do {                                           \
    const u16* p_ = ArBase + (bufi) * 16384 + (q) * 2048;                 \
    dst[0][0] = *(const short8*)(p_ + acb0);                              \
    dst[0][1] = *(const short8*)(p_ + acb1);                              \
    dst[1][0] = *(const short8*)(p_ + 1024 + acb0);                       \
    dst[1][1] = *(const short8*)(p_ + 1024 + acb1);                       \
  } while (0)

#define RD_B(bufi) do {                                                   \
    const u16* p_ = BrBase + (bufi) * 16384;                              \
    brg[0][0] = *(const short8*)(p_ + acb0);                              \
    brg[0][1] = *(const short8*)(p_ + acb1);                              \
    brg[1][0] = *(const short8*)(p_ + 1024 + acb0);                       \
    brg[1][1] = *(const short8*)(p_ + 1024 + acb1);                       \
    brg[2][0] = *(const short8*)(p_ + 2048 + acb0);                       \
    brg[2][1] = *(const short8*)(p_ + 2048 + acb1);                       \
    brg[3][0] = *(const short8*)(p_ + 3072 + acb0);                       \
    brg[3][1] = *(const short8*)(p_ + 3072 + acb1);                       \
  } while (0)

#define MFMA1(mi, jj, ar) do {                                                            \
    acc[mi][jj] = __builtin_amdgcn_mfma_f32_16x16x32_bf16(ar[0], brg[jj][0], acc[mi][jj], 0, 0, 0); \
    acc[mi][jj] = __builtin_amdgcn_mfma_f32_16x16x32_bf16(ar[1], brg[jj][1], acc[mi][jj], 0, 0, 0); \
  } while (0)

#define MFMA_Q(q, a) do {                                                 \
    MFMA1((q)*2 + 0, 0, a[0]); MFMA1((q)*2 + 0, 1, a[0]);                 \
    MFMA1((q)*2 + 0, 2, a[0]); MFMA1((q)*2 + 0, 3, a[0]);                 \
    MFMA1((q)*2 + 1, 0, a[1]); MFMA1((q)*2 + 1, 1, a[1]);                 \
    MFMA1((q)*2 + 1, 2, a[1]); MFMA1((q)*2 + 1, 3, a[1]);                 \
  } while (0)

#define ASM_VMCNT(n) asm volatile("s_waitcnt vmcnt(" #n ")" ::: "memory")
#define BAR() __builtin_amdgcn_s_barrier()
#define PRIO1 __builtin_amdgcn_s_setprio(1)
#define PRIO0 __builtin_amdgcn_s_setprio(0)

// S1: tile t+1 exists (stage A(t+1)h1, read its q0). S2: tile t+2 exists.
#define KGROUP(S1, S2, VMN) do {                                          \
    const int bi = t & 1, bn = bi ^ 1;                                    \
    /* ph1 */                                                             \
    RD_B(bi);                                                             \
    RD_A(aN, bi, 1);                                                      \
    if (S1) STAGE_A(bn, 1, t + 1);                                        \
    BAR();                                                                \
    PRIO1; MFMA_Q(0, aP); PRIO0;                                          \
    BAR();                                                                \
    /* ph2 */                                                             \
    RD_A(aP, bi, 2);                                                      \
    if (S2) STAGE_B(bi, 0, t + 2);                                        \
    BAR();                                                                \
    PRIO1; MFMA_Q(1, aN); PRIO0;                                          \
    BAR();                                                                \
    /* ph3 */                                                             \
    RD_A(aN, bi, 3);                                                      \
    if (S2) STAGE_B(bi, 1, t + 2);                                        \
    BAR();                                                                \
    PRIO1; MFMA_Q(2, aP); PRIO0;                                          \
    BAR();                                                                \
    /* ph4 */                                                             \
    ASM_VMCNT(VMN);                                                       \
    __builtin_amdgcn_sched_barrier(0);                                    \
    BAR();                                                                \
    if (S1) RD_A(aP, bn, 0);                                              \
    PRIO1; MFMA_Q(3, aN); PRIO0;                                          \
    if (S2) STAGE_A(bi, 0, t + 2);                                        \
    BAR();                                                                \
  } while (0)

  // ---- prologue: tile0 (4 halves) + B(1) (2 halves); vmcnt(4) retires tile0 ----
  STAGE_A(0, 0, 0); STAGE_A(0, 1, 0);
  STAGE_B(0, 0, 0); STAGE_B(0, 1, 0);
  STAGE_B(1, 0, 1); STAGE_B(1, 1, 1);
  ASM_VMCNT(4);
  __builtin_amdgcn_sched_barrier(0);
  BAR();
  STAGE_A(1, 0, 1);       // A(1)h0 in flight (mimics steady ph4 issue slot)
  RD_A(aP, 0, 0);         // tile0 quad0 into regs

  for (int t = 0; t < nt - 2; ++t) { KGROUP(1, 1, 4); }
  { int t = nt - 2; KGROUP(1, 0, 0); }   // drain: confirm last tile fully
  { int t = nt - 1; KGROUP(0, 0, 0); }

  // ---- epilogue ----
  if (mode == 0) {
#pragma unroll
    for (int mi = 0; mi < 8; ++mi)
#pragma unroll
      for (int r = 0; r < 4; ++r) {
        int row = m0 + wm * 128 + mi * 16 + quad * 4 + r;
        float* cp = C + (long)row * N + n0 + wn * 64 + l16;
#pragma unroll
        for (int jj = 0; jj < 4; ++jj) cp[jj * 16] = acc[mi][jj][r];
      }
  } else {
    // n-tile is 256 wide = 2 heads; which-of-q/k/v is block-uniform (256 | 5120)
    const int which = n0 / HID;
    const int hbase = (n0 % HID) >> 7;
    const float qs = 0.08838834764831845f;  // 1/sqrt(128), folded into q
#pragma unroll
    for (int mi = 0; mi < 8; ++mi)
#pragma unroll
      for (int jj = 0; jj < 4; ++jj) {
        int colIn = wn * 64 + jj * 16 + l16;   // 0..255
        int head = hbase + (colIn >> 7);
        int d = colIn & 127;
#pragma unroll
        for (int r = 0; r < 4; ++r) {
          int sI = m0 + wm * 128 + mi * 16 + quad * 4 + r;
          float v = acc[mi][jj][r];
          if (which == 0)      qb[((long)head * S + sI) * HD + d] = f2bf(v * qs);
          else if (which == 1) kb[((long)head * S + sI) * HD + d] = f2bf(v);
          else                 vtb[((long)head * HD + d) * S + sI] = f2bf(v);  // V^T
        }
      }
  }

#undef STAGE_A
#undef STAGE_B
#undef RD_A
#undef RD_B
#undef MFMA1
#undef MFMA_Q
#undef ASM_VMCNT
#undef BAR
#undef PRIO1
#undef PRIO0
#undef KGROUP
}

// ---------------- flash attention: Q-tile 64, K-tile 64 ----------------
// q,k: [NH][S][HD] bf16 (q pre-scaled), v: [NH][HD][S] bf16 (transposed)
// out: [S][HID] bf16
__global__ __launch_bounds__(256) void attn_kernel(
    const u16* __restrict__ qg, const u16* __restrict__ kg,
    const u16* __restrict__ vg, u16* __restrict__ og)
{
  __shared__ __align__(16) u16 Qs[64 * 128];   // [q][d]
  __shared__ __align__(16) u16 Ks[64 * 128];   // [k][d]; aliased by Ps[64][64]
  __shared__ __align__(16) u16 Vs[128 * 64];   // [d][k]  (V^T tile)
  __shared__ float redm[2][64];
  __shared__ float reds[2][64];

  const int tid = threadIdx.x;
  const int lane = tid & 63;
  const int wid = tid >> 6;
  const int wm = wid >> 1, wn = wid & 1;
  const int l16 = lane & 15, quad = lane >> 4;
  const int qt = blockIdx.x;
  const int h = blockIdx.y;
  const int q0 = qt * 64;

  u16* Ps = Ks;  // P overwrites K tile after S-compute (barrier-protected)

  {
    const u16* src = qg + ((long)h * S + q0) * HD;
#pragma unroll
    for (int cc = 0; cc < 4; ++cc) {
      int c = wid * 4 + cc;
      int row = c * 4 + (lane >> 4);
      int cb = (lane & 15) ^ (row & 7);
      gl_lds16(src + row * HD + cb * 8, &Qs[c * 512]);
    }
  }

  f32x4 acc_o[2][4];
#pragma unroll
  for (int i = 0; i < 2; ++i)
#pragma unroll
    for (int j = 0; j < 4; ++j)
      acc_o[i][j] = (f32x4){0.f, 0.f, 0.f, 0.f};
  float m_st[2][4], l_st[2][4];
#pragma unroll
  for (int i = 0; i < 2; ++i)
#pragma unroll
    for (int r = 0; r < 4; ++r) { m_st[i][r] = -1e30f; l_st[i][r] = 0.f; }

  for (int kt = 0; kt <= qt; ++kt) {
    __syncthreads();  // prev iter's Ps/Vs reads done (also covers Q stage on iter 0)
    {
      const u16* ksrc = kg + ((long)h * S + kt * 64) * HD;
#pragma unroll
      for (int cc = 0; cc < 4; ++cc) {
        int c = wid * 4 + cc;
        int row = c * 4 + (lane >> 4);
        int cb = (lane & 15) ^ (row & 7);
        gl_lds16(ksrc + row * HD + cb * 8, &Ks[c * 512]);
      }
      const u16* vsrc = vg + (long)h * HD * S + kt * 64;
#pragma unroll
      for (int cc = 0; cc < 4; ++cc) {
        int c = wid * 4 + cc;
        int row = c * 8 + (lane >> 3);
        int cb = (lane & 7) ^ (row & 7);
        gl_lds16(vsrc + (long)row * S + cb * 8, &Vs[c * 512]);
      }
    }
    __syncthreads();

    // ---- S = Q K^T (64x64, each wave 32x32) ----
    f32x4 acc_s[2][2];
#pragma unroll
    for (int i = 0; i < 2; ++i)
#pragma unroll
      for (int j = 0; j < 2; ++j)
        acc_s[i][j] = (f32x4){0.f, 0.f, 0.f, 0.f};
#pragma unroll
    for (int kk = 0; kk < 128; kk += 32) {
      short8 aq[2], bk[2];
      const int cb0 = (kk >> 3) + quad;
#pragma unroll
      for (int i = 0; i < 2; ++i) {
        int row = wm * 32 + i * 16 + l16;
        aq[i] = *(const short8*)&Qs[row * 128 + (cb0 ^ (row & 7)) * 8];
      }
#pragma unroll
      for (int j = 0; j < 2; ++j) {
        int row = wn * 32 + j * 16 + l16;
        bk[j] = *(const short8*)&Ks[row * 128 + (cb0 ^ (row & 7)) * 8];
      }
#pragma unroll
      for (int i = 0; i < 2; ++i)
#pragma unroll
        for (int j = 0; j < 2; ++j)
          acc_s[i][j] = __builtin_amdgcn_mfma_f32_16x16x32_bf16(aq[i], bk[j], acc_s[i][j], 0, 0, 0);
    }

    // ---- causal mask (only diagonal tile) ----
    if (kt == qt) {
#pragma unroll
      for (int i = 0; i < 2; ++i)
#pragma unroll
        for (int j = 0; j < 2; ++j)
#pragma unroll
          for (int r = 0; r < 4; ++r) {
            int row = wm * 32 + i * 16 + quad * 4 + r;
            int col = wn * 32 + j * 16 + l16;
            if (col > row) acc_s[i][j][r] = -1e30f;
          }
    }

    // ---- row max: per-wave shfl over 16 cols, cross-wave via LDS ----
#pragma unroll
    for (int i = 0; i < 2; ++i)
#pragma unroll
      for (int r = 0; r < 4; ++r) {
        float v = fmaxf(acc_s[i][0][r], acc_s[i][1][r]);
        v = fmaxf(v, __shfl_xor(v, 1));
        v = fmaxf(v, __shfl_xor(v, 2));
        v = fmaxf(v, __shfl_xor(v, 4));
        v = fmaxf(v, __shfl_xor(v, 8));
        if (l16 == 0) redm[wn][wm * 32 + i * 16 + quad * 4 + r] = v;
      }
    __syncthreads();  // redm ready; also: all waves done with Ks -> Ps writable

    float alpha[2][4], mnew[2][4], psum[2][4];
#pragma unroll
    for (int i = 0; i < 2; ++i)
#pragma unroll
      for (int r = 0; r < 4; ++r) {
        int row = wm * 32 + i * 16 + quad * 4 + r;
        float mn = fmaxf(m_st[i][r], fmaxf(redm[0][row], redm[1][row]));
        mnew[i][r] = mn;
        alpha[i][r] = __expf(m_st[i][r] - mn);
        m_st[i][r] = mn;
        psum[i][r] = 0.f;
      }
    // P = exp(S - mnew): write bf16 to Ps (C-layout -> LDS -> A-layout)
#pragma unroll
    for (int i = 0; i < 2; ++i)
#pragma unroll
      for (int j = 0; j < 2; ++j)
#pragma unroll
        for (int r = 0; r < 4; ++r) {
          int row = wm * 32 + i * 16 + quad * 4 + r;
          int col = wn * 32 + j * 16 + l16;
          float p = __expf(acc_s[i][j][r] - mnew[i][r]);
          psum[i][r] += p;
          Ps[row * 64 + ((col >> 3) ^ (row & 7)) * 8 + (col & 7)] = f2bf(p);
        }
#pragma unroll
    for (int i = 0; i < 2; ++i)
#pragma unroll
      for (int r = 0; r < 4; ++r) {
        float v = psum[i][r];
        v += __shfl_xor(v, 1);
        v += __shfl_xor(v, 2);
        v += __shfl_xor(v, 4);
        v += __shfl_xor(v, 8);
        if (l16 == 0) reds[wn][wm * 32 + i * 16 + quad * 4 + r] = v;
      }
    __syncthreads();  // Ps + reds ready

    // ---- rescale O, update l ----
#pragma unroll
    for (int i = 0; i < 2; ++i)
#pragma unroll
      for (int r = 0; r < 4; ++r) {
        int row = wm * 32 + i * 16 + quad * 4 + r;
        l_st[i][r] = alpha[i][r] * l_st[i][r] + reds[0][row] + reds[1][row];
#pragma unroll
        for (int j = 0; j < 4; ++j)
          acc_o[i][j][r] *= alpha[i][r];
      }
    // ---- O += P V   (each wave: rows wm*32+32, d-cols wn*64+64) ----
#pragma unroll
    for (int kk = 0; kk < 64; kk += 32) {
      short8 ap[2], bv[4];
      const int cb0 = (kk >> 3) + quad;
#pragma unroll
      for (int i = 0; i < 2; ++i) {
        int m = wm * 32 + i * 16 + l16;
        ap[i] = *(const short8*)&Ps[m * 64 + (cb0 ^ (m & 7)) * 8];
      }
#pragma unroll
      for (int j = 0; j < 4; ++j) {
        int n = wn * 64 + j * 16 + l16;
        bv[j] = *(const short8*)&Vs[n * 64 + (cb0 ^ (n & 7)) * 8];
      }
#pragma unroll
      for (int i = 0; i < 2; ++i)
#pragma unroll
        for (int j = 0; j < 4; ++j)
          acc_o[i][j] = __builtin_amdgcn_mfma_f32_16x16x32_bf16(ap[i], bv[j], acc_o[i][j], 0, 0, 0);
    }
  }

  // ---- epilogue: O / l -> bf16 [S][HID] ----
#pragma unroll
  for (int i = 0; i < 2; ++i)
#pragma unroll
    for (int r = 0; r < 4; ++r) {
      int row = wm * 32 + i * 16 + quad * 4 + r;
      float inv = 1.f / l_st[i][r];
#pragma unroll
      for (int j = 0; j < 4; ++j) {
        int d = wn * 64 + j * 16 + l16;
        og[(long)(q0 + row) * HID + h * HD + d] = f2bf(acc_o[i][j][r] * inv);
      }
    }
}

// ---------------- host ----------------
extern "C" void kernel_launch(void* const* d_in, const int* in_sizes, int n_in,
                              void* d_out, int out_size, void* d_ws, size_t ws_size,
                              hipStream_t stream) {
  const float* hs = (const float*)d_in[0];
  const float* wp = (const float*)d_in[1];
  const float* wo = (const float*)d_in[2];
  float* out = (float*)d_out;
  char* ws = (char*)d_ws;

  // ws layout (bytes)
  u16* hsb = (u16*)(ws);                  //  20,971,520  hs bf16 [2048][5120]
  u16* wpb = (u16*)(ws + 20971520L);      // 157,286,400  W_pack bf16 [15360][5120]
  u16* wob = (u16*)(ws + 178257920L);     //  52,428,800  o_proj bf16 [5120][5120]
  u16* qb  = (u16*)(ws + 230686720L);     //  20,971,520  q bf16 [40][2048][128] (scaled)
  u16* kb  = (u16*)(ws + 251658240L);     //  20,971,520  k bf16 [40][2048][128]
  u16* vtb = (u16*)(ws + 272629760L);     //  20,971,520  v^T bf16 [40][128][2048]
  u16* aob = (u16*)(ws + 293601280L);     //  20,971,520  attn out bf16 [2048][5120]
  if (ws_size < 314572800UL) return;      // need 300 MB

  cvt4<<<10240, 256, 0, stream>>>((const float4*)hs, (ushort4*)hsb, 2621440);
  cvt4<<<76800, 256, 0, stream>>>((const float4*)wp, (ushort4*)wpb, 19660800);
  cvt4<<<25600, 256, 0, stream>>>((const float4*)wo, (ushort4*)wob, 6553600);

  // QKV: [2048,15360] = hs @ W_pack^T, scatter to q/k/v^T
  // ntiles = 60 -> nslots 64 -> grid 8*64 = 512 (4 dead slots/XCD exit early)
  gemm256<<<dim3(512), dim3(512), 0, stream>>>(hsb, wpb, 15360, 5120,
                                               nullptr, qb, kb, vtb, 1);
  attn_kernel<<<dim3(32, 40), 256, 0, stream>>>(qb, kb, vtb, aob);
  // out: [2048,5120] = attn_out @ o_proj^T
  // ntiles = 20 -> nslots 24 -> grid 8*24 = 192
  gemm256<<<dim3(192), dim3(512), 0, stream>>>(aob, wob, 5120, 5120,
                                               out, nullptr, nullptr, nullptr, 0);
}

// Round 3
// 1474.465 us; speedup vs baseline: 1.1237x; 1.0448x over previous
//
#include <hip/hip_runtime.h>

#define S 2048
#define HID 5120
#define NH 40
#define HD 128

typedef unsigned short u16;
typedef __attribute__((ext_vector_type(8))) short short8;
typedef __attribute__((ext_vector_type(4))) float f32x4;

__device__ __forceinline__ u16 f2bf(float f) {
  union { float f; unsigned u; } x; x.f = f;
  unsigned r = x.u + 0x7fffu + ((x.u >> 16) & 1u);
  return (u16)(r >> 16);
}

// async global->LDS, 16B per lane; LDS dest = wave-uniform base + lane*16
__device__ __forceinline__ void gl_lds16(const void* g, void* l) {
  __builtin_amdgcn_global_load_lds((__attribute__((address_space(1))) void*)g,
                                   (__attribute__((address_space(3))) void*)l,
                                   16, 0, 0);
}

// ---------------- fp32 -> bf16 convert ----------------
__global__ __launch_bounds__(256) void cvt4(const float4* __restrict__ s,
                                            ushort4* __restrict__ d, int n4) {
  int i = blockIdx.x * 256 + threadIdx.x;
  if (i >= n4) return;
  float4 v = s[i];
  ushort4 o;
  o.x = f2bf(v.x); o.y = f2bf(v.y); o.z = f2bf(v.z); o.w = f2bf(v.w);
  d[i] = o;
}

// ---------------- 256x256 8-phase pipelined bf16 GEMM ----------------
// (unchanged from round 2 — control variable; see comments there)
__global__ __launch_bounds__(512, 2) void gemm256(
    const u16* __restrict__ A, const u16* __restrict__ B,
    int N, int K,
    float* __restrict__ C,
    u16* __restrict__ qb, u16* __restrict__ kb, u16* __restrict__ vtb,
    int mode)
{
  __shared__ __align__(16) u16 As[2][16384];   // [buf][256*64]
  __shared__ __align__(16) u16 Bs[2][16384];

  const int tid = threadIdx.x;
  const int lane = tid & 63;
  const int wave = tid >> 6;
  const int wm = wave >> 2, wn = wave & 3;
  const int l16 = lane & 15, quad = lane >> 4;

  // XCD-aware (m,n) mapping: co-schedule all 8 m's of an n-panel on one XCD
  const int xcd = blockIdx.x & 7;
  const int j = blockIdx.x >> 3;
  const int ntile = xcd + ((j >> 3) << 3);
  if (ntile >= (N >> 8)) return;               // padded slot: whole WG exits
  const int m0 = (j & 7) << 8;
  const int n0 = ntile << 8;

  const int srow = wave * 8 + (lane >> 3);            // row within half, load 0
  const int scb  = (lane & 7) ^ ((lane >> 3) & 7);    // pre-swizzled source col-block
  const u16* Abase = A + (long)(m0 + srow) * K + scb * 8;
  const u16* Bbase = B + (long)(n0 + srow) * K + scb * 8;
  u16* AsW = &As[0][0] + wave * 512;                  // wave-uniform LDS base
  u16* BsW = &Bs[0][0] + wave * 512;

  const u16* ArBase = &As[0][0] + (wm * 128 + l16) * 64;
  const u16* BrBase = &Bs[0][0] + (wn * 64 + l16) * 64;
  const int acb0 = ((quad) ^ (l16 & 7)) * 8;          // kk=0 col-block (swizzled)
  const int acb1 = ((4 + quad) ^ (l16 & 7)) * 8;      // kk=1

  f32x4 acc[8][4];
#pragma unroll
  for (int i = 0; i < 8; ++i)
#pragma unroll
    for (int j2 = 0; j2 < 4; ++j2) acc[i][j2] = (f32x4){0.f, 0.f, 0.f, 0.f};

  short8 aP[2][2], aN[2][2], brg[4][2];

  const int nt = K >> 6;   // 64-wide K-tiles (80 for K=5120)

#define STAGE_A(bufi, h, kt) do {                                         \
    const u16* g_ = Abase + (long)(h) * 128 * K + (long)(kt) * 64;        \
    gl_lds16(g_,           AsW + (bufi) * 16384 + (h) * 8192);            \
    gl_lds16(g_ + 64L * K, AsW + (bufi) * 16384 + (h) * 8192 + 4096);     \
  } while (0)

#define STAGE_B(bufi, h, kt) do {                                         \
    const u16* g_ = Bbase + (long)(h) * 128 * K + (long)(kt) * 64;        \
    gl_lds16(g_,           BsW + (bufi) * 16384 + (h) * 8192);            \
    gl_lds16(g_ + 64L * K, BsW + (bufi) * 16384 + (h) * 8192 + 4096);     \
  } while (0)

#define RD_A(dst, bufi, q) do {                                           \
    const u16* p_ = ArBase + (bufi) * 16384 + (q) * 2048;                 \
    dst[0][0] = *(const short8*)(p_ + acb0);                              \
    dst[0][1] = *(const short8*)(p_ + acb1);                              \
    dst[1][0] = *(const short8*)(p_ + 1024 + acb0);                       \
    dst[1][1] = *(const short8*)(p_ + 1024 + acb1);                       \
  } while (0)

#define RD_B(bufi) do {                                                   \
    const u16* p_ = BrBase + (bufi) * 16384;                              \
    brg[0][0] = *(const short8*)(p_ + acb0);                              \
    brg[0][1] = *(const short8*)(p_ + acb1);                              \
    brg[1][0] = *(const short8*)(p_ + 1024 + acb0);                       \
    brg[1][1] = *(const short8*)(p_ + 1024 + acb1);                       \
    brg[2][0] = *(const short8*)(p_ + 2048 + acb0);                       \
    brg[2][1] = *(const short8*)(p_ + 2048 + acb1);                       \
    brg[3][0] = *(const short8*)(p_ + 3072 + acb0);                       \
    brg[3][1] = *(const short8*)(p_ + 3072 + acb1);                       \
  } while (0)

#define MFMA1(mi, jj, ar) do {                                                            \
    acc[mi][jj] = __builtin_amdgcn_mfma_f32_16x16x32_bf16(ar[0], brg[jj][0], acc[mi][jj], 0, 0, 0); \
    acc[mi][jj] = __builtin_amdgcn_mfma_f32_16x16x32_bf16(ar[1], brg[jj][1], acc[mi][jj], 0, 0, 0); \
  } while (0)

#define MFMA_Q(q, a) do {                                                 \
    MFMA1((q)*2 + 0, 0, a[0]); MFMA1((q)*2 + 0, 1, a[0]);                 \
    MFMA1((q)*2 + 0, 2, a[0]); MFMA1((q)*2 + 0, 3, a[0]);                 \
    MFMA1((q)*2 + 1, 0, a[1]); MFMA1((q)*2 + 1, 1, a[1]);                 \
    MFMA1((q)*2 + 1, 2, a[1]); MFMA1((q)*2 + 1, 3, a[1]);                 \
  } while (0)

#define ASM_VMCNT(n) asm volatile("s_waitcnt vmcnt(" #n ")" ::: "memory")
#define BAR() __builtin_amdgcn_s_barrier()
#define PRIO1 __builtin_amdgcn_s_setprio(1)
#define PRIO0 __builtin_amdgcn_s_setprio(0)

#define KGROUP(S1, S2, VMN) do {                                          \
    const int bi = t & 1, bn = bi ^ 1;                                    \
    /* ph1 */                                                             \
    RD_B(bi);                                                             \
    RD_A(aN, bi, 1);                                                      \
    if (S1) STAGE_A(bn, 1, t + 1);                                        \
    BAR();                                                                \
    PRIO1; MFMA_Q(0, aP); PRIO0;                                          \
    BAR();                                                                \
    /* ph2 */                                                             \
    RD_A(aP, bi, 2);                                                      \
    if (S2) STAGE_B(bi, 0, t + 2);                                        \
    BAR();                                                                \
    PRIO1; MFMA_Q(1, aN); PRIO0;                                          \
    BAR();                                                                \
    /* ph3 */                                                             \
    RD_A(aN, bi, 3);                                                      \
    if (S2) STAGE_B(bi, 1, t + 2);                                        \
    BAR();                                                                \
    PRIO1; MFMA_Q(2, aP); PRIO0;                                          \
    BAR();                                                                \
    /* ph4 */                                                             \
    ASM_VMCNT(VMN);                                                       \
    __builtin_amdgcn_sched_barrier(0);                                    \
    BAR();                                                                \
    if (S1) RD_A(aP, bn, 0);                                              \
    PRIO1; MFMA_Q(3, aN); PRIO0;                                          \
    if (S2) STAGE_A(bi, 0, t + 2);                                        \
    BAR();                                                                \
  } while (0)

  STAGE_A(0, 0, 0); STAGE_A(0, 1, 0);
  STAGE_B(0, 0, 0); STAGE_B(0, 1, 0);
  STAGE_B(1, 0, 1); STAGE_B(1, 1, 1);
  ASM_VMCNT(4);
  __builtin_amdgcn_sched_barrier(0);
  BAR();
  STAGE_A(1, 0, 1);       // A(1)h0 in flight (mimics steady ph4 issue slot)
  RD_A(aP, 0, 0);         // tile0 quad0 into regs

  for (int t = 0; t < nt - 2; ++t) { KGROUP(1, 1, 4); }
  { int t = nt - 2; KGROUP(1, 0, 0); }   // drain: confirm last tile fully
  { int t = nt - 1; KGROUP(0, 0, 0); }

  if (mode == 0) {
#pragma unroll
    for (int mi = 0; mi < 8; ++mi)
#pragma unroll
      for (int r = 0; r < 4; ++r) {
        int row = m0 + wm * 128 + mi * 16 + quad * 4 + r;
        float* cp = C + (long)row * N + n0 + wn * 64 + l16;
#pragma unroll
        for (int jj = 0; jj < 4; ++jj) cp[jj * 16] = acc[mi][jj][r];
      }
  } else {
    const int which = n0 / HID;
    const int hbase = (n0 % HID) >> 7;
    const float qs = 0.08838834764831845f;  // 1/sqrt(128), folded into q
#pragma unroll
    for (int mi = 0; mi < 8; ++mi)
#pragma unroll
      for (int jj = 0; jj < 4; ++jj) {
        int colIn = wn * 64 + jj * 16 + l16;   // 0..255
        int head = hbase + (colIn >> 7);
        int d = colIn & 127;
#pragma unroll
        for (int r = 0; r < 4; ++r) {
          int sI = m0 + wm * 128 + mi * 16 + quad * 4 + r;
          float v = acc[mi][jj][r];
          if (which == 0)      qb[((long)head * S + sI) * HD + d] = f2bf(v * qs);
          else if (which == 1) kb[((long)head * S + sI) * HD + d] = f2bf(v);
          else                 vtb[((long)head * HD + d) * S + sI] = f2bf(v);  // V^T
        }
      }
  }

#undef STAGE_A
#undef STAGE_B
#undef RD_A
#undef RD_B
#undef MFMA1
#undef MFMA_Q
#undef ASM_VMCNT
#undef BAR
#undef PRIO1
#undef PRIO0
#undef KGROUP
}

// ---------------- flash attention v2: Q-tile 128, 8 waves, wave-local softmax ----------------
// q,k: [NH][S][HD] bf16 (q pre-scaled), v: [NH][HD][S] bf16 (transposed), out: [S][HID] bf16
// Wave w owns q-rows [w*16, w*16+16). Q hoisted to registers (Qs LDS aliased by K dbuf).
// K/V double-buffered, staged one full iteration ahead; ONE __syncthreads per K-tile.
// LDS pool (80 KB -> 2 blocks/CU):
//   bytes [0,32K):  Qs[128][128] (transient)  ALIAS  Ks[2][64][128]
//   bytes [32K,64K): Vs[2][128][64]  (V^T tiles)
//   bytes [64K,80K): Ps[128][64]
// All tiles XOR-swizzled on 16B col-blocks: LDS[row][cb] = G[row][cb ^ (row&7)].
__device__ __forceinline__ void stage_kv(const u16* __restrict__ ksrc0,
                                         const u16* __restrict__ vsrc0,
                                         u16* pool, int buf, int t,
                                         int wave, int lane) {
  const u16* ks_ = ksrc0 + (long)t * 64 * HD;
  const u16* vs_ = vsrc0 + t * 64;
#pragma unroll
  for (int cc = 0; cc < 2; ++cc) {
    int c = wave * 2 + cc;
    int row = c * 4 + (lane >> 4);              // 0..63 (k-seq)
    int cb = (lane & 15) ^ (row & 7);
    gl_lds16(ks_ + row * HD + cb * 8, &pool[buf * 8192 + c * 512]);
  }
#pragma unroll
  for (int cc = 0; cc < 2; ++cc) {
    int c = wave * 2 + cc;
    int row = c * 8 + (lane >> 3);              // 0..127 (d)
    int cb = (lane & 7) ^ (row & 7);
    gl_lds16(vs_ + (long)row * S + cb * 8, &pool[16384 + buf * 8192 + c * 512]);
  }
}

__global__ __launch_bounds__(512, 4) void attn_kernel(
    const u16* __restrict__ qg, const u16* __restrict__ kg,
    const u16* __restrict__ vg, u16* __restrict__ og)
{
  __shared__ __align__(16) u16 pool[40960];   // 80 KB

  const int tid = threadIdx.x;
  const int lane = tid & 63;
  const int wave = tid >> 6;
  const int l16 = lane & 15, quad = lane >> 4;
  const int qt = (int)gridDim.x - 1 - (int)blockIdx.x;   // long blocks first
  const int h = blockIdx.y;
  const int q0 = qt * 128;
  const int nkt = 2 * qt + 2;                  // 64-wide K-tiles (>= 2)

  u16* Qs = pool;                              // transient, aliases Ks
  u16* Ps = pool + 32768;

  // ---- stage Q [128][128] and hoist to registers ----
  {
    const u16* src = qg + ((long)h * S + q0) * HD;
#pragma unroll
    for (int cc = 0; cc < 4; ++cc) {
      int c = wave * 4 + cc;
      int row = c * 4 + (lane >> 4);
      int cb = (lane & 15) ^ (row & 7);
      gl_lds16(src + row * HD + cb * 8, &Qs[c * 512]);
    }
  }
  __syncthreads();
  short8 aq[4];
  {
    const int row = wave * 16 + l16;
    const u16* qr = &Qs[row * 128];
    const int sw = row & 7;
#pragma unroll
    for (int ks = 0; ks < 4; ++ks)
      aq[ks] = *(const short8*)(qr + ((ks * 4 + quad) ^ sw) * 8);
  }
  __syncthreads();   // all waves have Q in regs before K staging overwrites Qs

  const u16* ksrc0 = kg + (long)h * S * HD;
  const u16* vsrc0 = vg + (long)h * HD * S;

  // ---- prologue: tiles 0,1 staged; tile 0 confirmed, tile 1 in flight ----
  stage_kv(ksrc0, vsrc0, pool, 0, 0, wave, lane);
  stage_kv(ksrc0, vsrc0, pool, 1, 1, wave, lane);
  asm volatile("s_waitcnt vmcnt(4)" ::: "memory");
  __builtin_amdgcn_sched_barrier(0);
  __builtin_amdgcn_s_barrier();

  f32x4 acc_o[8];
#pragma unroll
  for (int j2 = 0; j2 < 8; ++j2) acc_o[j2] = (f32x4){0.f, 0.f, 0.f, 0.f};
  float m_st[4], l_st[4];
#pragma unroll
  for (int r = 0; r < 4; ++r) { m_st[r] = -1e30f; l_st[r] = 0.f; }

  const int prow = wave * 16 + quad * 4;       // base q-row (in-tile) of this lane
  const int rowA = wave * 16 + l16;            // A-frag row (in-tile)
  const int swA = rowA & 7;

  for (int t = 0; t < nkt; ++t) {
    const int cur = t & 1;
    const u16* Ks = &pool[cur * 8192];
    const u16* Vs = &pool[16384 + cur * 8192];

    // ---- S = Q K^T : wave computes 16 rows x 64 cols ----
    f32x4 acc_s[4];
#pragma unroll
    for (int j2 = 0; j2 < 4; ++j2) acc_s[j2] = (f32x4){0.f, 0.f, 0.f, 0.f};
#pragma unroll
    for (int ks = 0; ks < 4; ++ks) {
      short8 bk[4];
#pragma unroll
      for (int j2 = 0; j2 < 4; ++j2) {
        int row = j2 * 16 + l16;               // k-seq index
        bk[j2] = *(const short8*)&Ks[row * 128 + (((ks * 4 + quad) ^ (row & 7)) * 8)];
      }
      __builtin_amdgcn_s_setprio(1);
#pragma unroll
      for (int j2 = 0; j2 < 4; ++j2)
        acc_s[j2] = __builtin_amdgcn_mfma_f32_16x16x32_bf16(aq[ks], bk[j2], acc_s[j2], 0, 0, 0);
      __builtin_amdgcn_s_setprio(0);
    }

    // ---- causal mask (last two K-tiles only) ----
    if (t >= nkt - 2) {
#pragma unroll
      for (int j2 = 0; j2 < 4; ++j2)
#pragma unroll
        for (int r = 0; r < 4; ++r) {
          int row_abs = q0 + prow + r;
          int col_abs = t * 64 + j2 * 16 + l16;
          if (col_abs > row_abs) acc_s[j2][r] = -1e30f;
        }
    }

    // ---- wave-local online softmax ----
    float mnew[4], alpha[4], psum[4];
#pragma unroll
    for (int r = 0; r < 4; ++r) {
      float v = fmaxf(fmaxf(acc_s[0][r], acc_s[1][r]), fmaxf(acc_s[2][r], acc_s[3][r]));
      v = fmaxf(v, __shfl_xor(v, 1));
      v = fmaxf(v, __shfl_xor(v, 2));
      v = fmaxf(v, __shfl_xor(v, 4));
      v = fmaxf(v, __shfl_xor(v, 8));
      float mn = fmaxf(m_st[r], v);
      mnew[r] = mn;
      alpha[r] = __expf(m_st[r] - mn);
      m_st[r] = mn;
      psum[r] = 0.f;
    }
#pragma unroll
    for (int j2 = 0; j2 < 4; ++j2)
#pragma unroll
      for (int r = 0; r < 4; ++r) {
        int row = prow + r;
        int colL = j2 * 16 + l16;
        float p = __expf(acc_s[j2][r] - mnew[r]);
        psum[r] += p;
        Ps[row * 64 + (((colL >> 3) ^ (row & 7)) * 8) + (colL & 7)] = f2bf(p);
      }
#pragma unroll
    for (int r = 0; r < 4; ++r) {
      float v = psum[r];
      v += __shfl_xor(v, 1);
      v += __shfl_xor(v, 2);
      v += __shfl_xor(v, 4);
      v += __shfl_xor(v, 8);
      l_st[r] = alpha[r] * l_st[r] + v;
#pragma unroll
      for (int j2 = 0; j2 < 8; ++j2) acc_o[j2][r] *= alpha[r];
    }

    // ---- O += P V : wave computes its 16 rows x 128 d ----
#pragma unroll
    for (int ks = 0; ks < 2; ++ks) {
      short8 ap = *(const short8*)&Ps[rowA * 64 + (((ks * 4 + quad) ^ swA) * 8)];
      short8 bv[8];
#pragma unroll
      for (int j2 = 0; j2 < 8; ++j2) {
        int d = j2 * 16 + l16;
        bv[j2] = *(const short8*)&Vs[d * 64 + (((ks * 4 + quad) ^ (d & 7)) * 8)];
      }
      __builtin_amdgcn_s_setprio(1);
#pragma unroll
      for (int j2 = 0; j2 < 8; ++j2)
        acc_o[j2] = __builtin_amdgcn_mfma_f32_16x16x32_bf16(ap, bv[j2], acc_o[j2], 0, 0, 0);
      __builtin_amdgcn_s_setprio(0);
    }

    // ---- pipeline: confirm tile t+1, launch tile t+2 into buf[cur] ----
    if (t + 1 < nkt) {
      __syncthreads();   // drains vmcnt+lgkm: tile t+1 visible; buf[cur] reads done
      if (t + 2 < nkt) stage_kv(ksrc0, vsrc0, pool, cur, t + 2, wave, lane);
    }
  }

  // ---- epilogue: O / l -> bf16 [S][HID] ----
#pragma unroll
  for (int r = 0; r < 4; ++r) {
    float inv = 1.f / l_st[r];
    u16* op = og + (long)(q0 + prow + r) * HID + h * HD + l16;
#pragma unroll
    for (int j2 = 0; j2 < 8; ++j2)
      op[j2 * 16] = f2bf(acc_o[j2][r] * inv);
  }
}

// ---------------- host ----------------
extern "C" void kernel_launch(void* const* d_in, const int* in_sizes, int n_in,
                              void* d_out, int out_size, void* d_ws, size_t ws_size,
                              hipStream_t stream) {
  const float* hs = (const float*)d_in[0];
  const float* wp = (const float*)d_in[1];
  const float* wo = (const float*)d_in[2];
  float* out = (float*)d_out;
  char* ws = (char*)d_ws;

  // ws layout (bytes)
  u16* hsb = (u16*)(ws);                  //  20,971,520  hs bf16 [2048][5120]
  u16* wpb = (u16*)(ws + 20971520L);      // 157,286,400  W_pack bf16 [15360][5120]
  u16* wob = (u16*)(ws + 178257920L);     //  52,428,800  o_proj bf16 [5120][5120]
  u16* qb  = (u16*)(ws + 230686720L);     //  20,971,520  q bf16 [40][2048][128] (scaled)
  u16* kb  = (u16*)(ws + 251658240L);     //  20,971,520  k bf16 [40][2048][128]
  u16* vtb = (u16*)(ws + 272629760L);     //  20,971,520  v^T bf16 [40][128][2048]
  u16* aob = (u16*)(ws + 293601280L);     //  20,971,520  attn out bf16 [2048][5120]
  if (ws_size < 314572800UL) return;      // need 300 MB

  cvt4<<<10240, 256, 0, stream>>>((const float4*)hs, (ushort4*)hsb, 2621440);
  cvt4<<<76800, 256, 0, stream>>>((const float4*)wp, (ushort4*)wpb, 19660800);
  cvt4<<<25600, 256, 0, stream>>>((const float4*)wo, (ushort4*)wob, 6553600);

  // QKV: [2048,15360] = hs @ W_pack^T, scatter to q/k/v^T
  gemm256<<<dim3(512), dim3(512), 0, stream>>>(hsb, wpb, 15360, 5120,
                                               nullptr, qb, kb, vtb, 1);
  // attention: 16 q-tiles of 128 x 40 heads, 512 threads
  attn_kernel<<<dim3(16, 40), 512, 0, stream>>>(qb, kb, vtb, aob);
  // out: [2048,5120] = attn_out @ o_proj^T
  gemm256<<<dim3(192), dim3(512), 0, stream>>>(aob, wob, 5120, 5120,
                                               out, nullptr, nullptr, nullptr, 0);
}